// Round 1
// baseline (195.111 us; speedup 1.0000x reference)
//
#include <hip/hip_runtime.h>
#include <hip/hip_bf16.h>
#include <math.h>

#define NN 60000
#define D 300
#define R 5
#define NE 1000000
#define B 32
#define NG 25000
#define NS 25000
#define NROWS 50000
#define TJ 128

// ws layout (floats):
// [0, 48000)        sum[b][r][d]
// [48000, 48160)    cnt[b][r]
// [48160, 57760)    hc[b][d]

__global__ void edge_scan(const int* __restrict__ ei, const int* __restrict__ et,
                          const float* __restrict__ x, const int* __restrict__ cur,
                          float* __restrict__ wsum, float* __restrict__ wcnt) {
    __shared__ unsigned int tbl[32];
    __shared__ int curl[B];
    int tid = threadIdx.x;
    if (tid < 32) tbl[tid] = 0u;
    __syncthreads();
    if (tid < B) {
        int c = cur[tid];
        curl[tid] = c;
        atomicOr(&tbl[(c >> 5) & 31], 1u << (c & 31));
    }
    __syncthreads();
    int e = blockIdx.x * blockDim.x + tid;
    if (e >= NE) return;
    int dst = ei[NE + e];
    if (!(tbl[(dst >> 5) & 31] & (1u << (dst & 31)))) return;  // bloom reject (~97%)
    int src = -1, r = 0;
    for (int b = 0; b < B; ++b) {
        if (dst == curl[b]) {
            if (src < 0) { src = ei[e]; r = et[e]; }
            atomicAdd(&wcnt[b * R + r], 1.0f);
            const float* xs = x + (long)src * D;
            float* sm = wsum + (b * R + r) * D;
            for (int d = 0; d < D; ++d) atomicAdd(&sm[d], xs[d]);
        }
    }
}

__global__ void hc_kernel(const float* __restrict__ x, const int* __restrict__ cur,
                          const float* __restrict__ basis, const float* __restrict__ comp,
                          const float* __restrict__ root, const float* __restrict__ bias,
                          const float* __restrict__ wsum, const float* __restrict__ wcnt,
                          float* __restrict__ hc) {
    int b = blockIdx.x;
    int tid = threadIdx.x;
    __shared__ float invs[R];
    __shared__ float meanl[R * D];
    __shared__ float mcl[R * D];
    __shared__ float xl[D];
    if (tid < R) invs[tid] = 1.0f / fmaxf(wcnt[b * R + tid], 1.0f);
    int node = cur[b];
    for (int i = tid; i < D; i += blockDim.x) xl[i] = x[(long)node * D + i];
    __syncthreads();
    for (int i = tid; i < R * D; i += blockDim.x) {
        int r = i / D;
        meanl[i] = wsum[b * R * D + i] * invs[r];
    }
    __syncthreads();
    for (int i = tid; i < R * D; i += blockDim.x) {
        int bb = i / D, d = i - bb * D;
        float a = 0.f;
        #pragma unroll
        for (int r = 0; r < R; ++r) a = fmaf(comp[r * R + bb], meanl[r * D + d], a);
        mcl[i] = a;
    }
    __syncthreads();
    for (int e = tid; e < D; e += blockDim.x) {
        float acc = bias[e];
        for (int d = 0; d < D; ++d) acc = fmaf(xl[d], root[d * D + e], acc);
        #pragma unroll
        for (int bb = 0; bb < R; ++bb) {
            const float* bp = basis + ((long)bb * D) * D + e;
            const float* mp = mcl + bb * D;
            for (int d = 0; d < D; ++d) acc = fmaf(mp[d], bp[(long)d * D], acc);
        }
        hc[b * D + e] = fmaxf(acc, 0.0f);
    }
}

__global__ __launch_bounds__(256) void head_gemm(
    const float* __restrict__ hc, const float* __restrict__ wg, const float* __restrict__ bg,
    const float* __restrict__ wsn, const float* __restrict__ bsn, float* __restrict__ out) {
    __shared__ float hL[B * D];  // 38.4 KB, staged once, reused over all K
    int tid = threadIdx.x;
    for (int i = tid; i < B * D / 4; i += 256)
        ((float4*)hL)[i] = ((const float4*)hc)[i];
    __syncthreads();

    int tj = tid & 31, tb = tid >> 5;
    int j0 = blockIdx.x * TJ + tj * 4;
    const float* wp[4];
    #pragma unroll
    for (int jj = 0; jj < 4; ++jj) {
        int j = j0 + jj;
        if (j > NROWS - 1) j = NROWS - 1;  // clamp: garbage acc, store guarded
        wp[jj] = (j < NG) ? (wg + (long)j * D) : (wsn + (long)(j - NG) * D);
    }
    const float* hp = hL + (tb * 4) * D;

    float acc[4][4] = {};
    for (int k = 0; k < D; k += 4) {
        float4 wv[4], hv[4];
        #pragma unroll
        for (int jj = 0; jj < 4; ++jj) wv[jj] = *(const float4*)(wp[jj] + k);
        #pragma unroll
        for (int bb = 0; bb < 4; ++bb) hv[bb] = *(const float4*)(hp + bb * D + k);
        #pragma unroll
        for (int jj = 0; jj < 4; ++jj) {
            #pragma unroll
            for (int bb = 0; bb < 4; ++bb) {
                acc[jj][bb] = fmaf(wv[jj].x, hv[bb].x, acc[jj][bb]);
                acc[jj][bb] = fmaf(wv[jj].y, hv[bb].y, acc[jj][bb]);
                acc[jj][bb] = fmaf(wv[jj].z, hv[bb].z, acc[jj][bb]);
                acc[jj][bb] = fmaf(wv[jj].w, hv[bb].w, acc[jj][bb]);
            }
        }
    }

    #pragma unroll
    for (int jj = 0; jj < 4; ++jj) {
        int j = j0 + jj;
        if (j >= NROWS) continue;
        float bv = (j < NG) ? bg[j] : bsn[j - NG];
        #pragma unroll
        for (int bb = 0; bb < 4; ++bb) {
            int b = tb * 4 + bb;
            float v = acc[jj][bb] + bv;
            float* op = (j < NG) ? (out + (long)b * NG + j)
                                 : (out + (long)B * NG + (long)b * NS + (j - NG));
            *op = v;
        }
    }
}

__global__ void log_softmax_rows(float* __restrict__ out) {
    int row = blockIdx.x;  // 0..63
    int head = row >> 5, b = row & 31;
    float* p = out + (long)head * (B * NG) + (long)b * NG;
    int tid = threadIdx.x;
    __shared__ float red[8];
    float m = -INFINITY;
    for (int i = tid; i < NG; i += 256) m = fmaxf(m, p[i]);
    #pragma unroll
    for (int off = 32; off; off >>= 1) m = fmaxf(m, __shfl_xor(m, off));
    if ((tid & 63) == 0) red[tid >> 6] = m;
    __syncthreads();
    if (tid == 0) {
        float mm = fmaxf(fmaxf(red[0], red[1]), fmaxf(red[2], red[3]));
        red[0] = mm;
    }
    __syncthreads();
    m = red[0];
    float s = 0.f;
    for (int i = tid; i < NG; i += 256) s += __expf(p[i] - m);
    #pragma unroll
    for (int off = 32; off; off >>= 1) s += __shfl_xor(s, off);
    if ((tid & 63) == 0) red[4 + (tid >> 6)] = s;
    __syncthreads();
    if (tid == 0) {
        float ss = red[4] + red[5] + red[6] + red[7];
        red[4] = m + __logf(ss);
    }
    __syncthreads();
    float lse = red[4];
    for (int i = tid; i < NG; i += 256) p[i] -= lse;
}

extern "C" void kernel_launch(void* const* d_in, const int* in_sizes, int n_in,
                              void* d_out, int out_size, void* d_ws, size_t ws_size,
                              hipStream_t stream) {
    const float* x     = (const float*)d_in[0];
    const int*   ei    = (const int*)d_in[1];
    const int*   et    = (const int*)d_in[2];
    const int*   cur   = (const int*)d_in[3];
    const float* basis = (const float*)d_in[4];
    const float* comp  = (const float*)d_in[5];
    const float* root  = (const float*)d_in[6];
    const float* bias  = (const float*)d_in[7];
    const float* wg    = (const float*)d_in[8];
    const float* bgl   = (const float*)d_in[9];
    const float* wsn   = (const float*)d_in[10];
    const float* bsn   = (const float*)d_in[11];
    float* out  = (float*)d_out;
    float* wsum = (float*)d_ws;
    float* wcnt = wsum + B * R * D;
    float* hc   = wcnt + B * R;

    hipMemsetAsync(d_ws, 0, (size_t)(B * R * D + B * R) * sizeof(float), stream);
    edge_scan<<<(NE + 255) / 256, 256, 0, stream>>>(ei, et, x, cur, wsum, wcnt);
    hc_kernel<<<B, 320, 0, stream>>>(x, cur, basis, comp, root, bias, wsum, wcnt, hc);
    head_gemm<<<(NROWS + TJ - 1) / TJ, 256, 0, stream>>>(hc, wg, bgl, wsn, bsn, out);
    log_softmax_rows<<<64, 256, 0, stream>>>(out);
}

// Round 2
// 106.530 us; speedup vs baseline: 1.8315x; 1.8315x over previous
//
#include <hip/hip_runtime.h>
#include <hip/hip_bf16.h>
#include <math.h>

#define NN 60000
#define D 300
#define R 5
#define NE 1000000
#define B 32
#define NG 25000
#define NS 25000
#define NROWS 50000
#define TJ 64
#define KC 60          // k-chunk for head_gemm (5 chunks of 60 = 300)
#define KCH 50         // d-rows per block in rgcn partial gemm
#define NKC 36         // 1800 / 50

// ws layout (floats): wsum[32*5*300]=48000, wcnt[160], hcp[32*300]=9600  (231KB, same as round 1)
// d_out tail scratch: part at out+0 (36*32*300=345600 floats), U at out+400000 (57600 floats).
// Both are consumed before head_gemm, which overwrites all of d_out.

__global__ void edge_scan(const int* __restrict__ ei, const int* __restrict__ et,
                          const float* __restrict__ x, const int* __restrict__ cur,
                          float* __restrict__ wsum, float* __restrict__ wcnt) {
    __shared__ unsigned int tbl[32];
    __shared__ int curl[B];
    int tid = threadIdx.x;
    if (tid < 32) tbl[tid] = 0u;
    __syncthreads();
    if (tid < B) {
        int c = cur[tid];
        curl[tid] = c;
        atomicOr(&tbl[(c >> 5) & 31], 1u << (c & 31));
    }
    __syncthreads();
    int e = blockIdx.x * blockDim.x + tid;
    if (e >= NE) return;
    int dst = ei[NE + e];
    if (!(tbl[(dst >> 5) & 31] & (1u << (dst & 31)))) return;  // bloom reject (~97%)
    int src = -1, r = 0;
    for (int b = 0; b < B; ++b) {
        if (dst == curl[b]) {
            if (src < 0) { src = ei[e]; r = et[e]; }
            atomicAdd(&wcnt[b * R + r], 1.0f);
            const float* xs = x + (long)src * D;
            float* sm = wsum + (b * R + r) * D;
            for (int d = 0; d < D; ++d) atomicAdd(&sm[d], xs[d]);
        }
    }
}

// Build U[b][1800] = concat(x[cur[b]], mc[0..4]) where mc[bb] = sum_r comp[r][bb]*mean[r]
__global__ void stage_u(const float* __restrict__ x, const int* __restrict__ cur,
                        const float* __restrict__ comp,
                        const float* __restrict__ wsum, const float* __restrict__ wcnt,
                        float* __restrict__ U) {
    int b = blockIdx.x, t = threadIdx.x;  // 320 threads
    __shared__ float cmp[R * R];
    __shared__ float inv[R];
    if (t < R * R) cmp[t] = comp[t];
    if (t < R) inv[t] = 1.0f / fmaxf(wcnt[b * R + t], 1.0f);
    __syncthreads();
    if (t >= D) return;
    int node = cur[b];
    U[(long)b * 1800 + t] = x[(long)node * D + t];
    float mean[R];
    #pragma unroll
    for (int r = 0; r < R; ++r) mean[r] = wsum[((long)b * R + r) * D + t] * inv[r];
    #pragma unroll
    for (int bb = 0; bb < R; ++bb) {
        float a = 0.f;
        #pragma unroll
        for (int r = 0; r < R; ++r) a = fmaf(cmp[r * R + bb], mean[r], a);
        U[(long)b * 1800 + 300 + bb * 300 + t] = a;
    }
}

// partial[kc][b][e] = sum_{d in chunk} U[b][d] * M[d][e],  M = [root; basis] stacked (1800 x 300)
__global__ __launch_bounds__(320) void rgcn_part(const float* __restrict__ root,
                                                 const float* __restrict__ basis,
                                                 const float* __restrict__ U,
                                                 float* __restrict__ part) {
    int kc = blockIdx.x, t = threadIdx.x;  // 320 threads, e = t
    __shared__ float uL[B * KCH];
    int d0 = kc * KCH;
    for (int i = t; i < B * KCH; i += 320) {
        int b = i / KCH, dd = i - b * KCH;
        uL[i] = U[(long)b * 1800 + d0 + dd];
    }
    __syncthreads();
    if (t >= D) return;
    const float* Mbase = (d0 < 300) ? (root + (long)d0 * D) : (basis + (long)(d0 - 300) * D);
    float acc[B] = {};
    #pragma unroll 5
    for (int i = 0; i < KCH; ++i) {
        float m = Mbase[(long)i * D + t];
        #pragma unroll
        for (int b = 0; b < B; ++b) acc[b] = fmaf(uL[b * KCH + i], m, acc[b]);
    }
    for (int b = 0; b < B; ++b) part[((long)kc * B + b) * D + t] = acc[b];
}

__global__ void finish_hc(const float* __restrict__ part, const float* __restrict__ bias,
                          float* __restrict__ hcp) {
    int b = blockIdx.x, t = threadIdx.x;  // 320 threads
    if (t >= D) return;
    float a = bias[t];
    for (int kc = 0; kc < NKC; ++kc) a += part[((long)kc * B + b) * D + t];
    hcp[b * D + t] = fmaxf(a, 0.f);
}

// out[b][j] over j in [0,50000): LDS-chunked f32 GEMM. Block: 64 j-rows, all 32 b.
__global__ __launch_bounds__(256) void head_gemm(
    const float* __restrict__ hc, const float* __restrict__ wg, const float* __restrict__ bg,
    const float* __restrict__ wsn, const float* __restrict__ bsn, float* __restrict__ out) {
    __shared__ float wL[TJ * KC];  // 64 x 60 = 15.36 KB, linear [row][k]
    __shared__ float hL[B * KC];   // 32 x 60 = 7.68 KB, linear [b][k]
    int tid = threadIdx.x;
    int j0 = blockIdx.x * TJ;
    int tj = tid & 31, tb = tid >> 5;  // 32 j-threads (2 rows each), 8 b-threads (4 b each)
    float acc[2][4] = {};

    for (int c = 0; c < 5; ++c) {
        int kc = c * KC;
        if (c) __syncthreads();
        // stage W chunk: 960 float4 slots, slot s -> row s/15, q s%15  (linear in LDS)
        for (int s = tid; s < TJ * 15; s += 256) {
            int row = s / 15, q = s - row * 15;
            int j = j0 + row; if (j >= NROWS) j = NROWS - 1;
            const float* src = (j < NG) ? (wg + (long)j * D) : (wsn + (long)(j - NG) * D);
            ((float4*)wL)[s] = *(const float4*)(src + kc + q * 4);
        }
        // stage hc chunk: 480 float4 slots
        for (int s = tid; s < B * 15; s += 256) {
            int b = s / 15, q = s - b * 15;
            ((float4*)hL)[s] = *(const float4*)(hc + b * D + kc + q * 4);
        }
        __syncthreads();
        const float4* wL4 = (const float4*)wL;
        const float4* hL4 = (const float4*)hL;
        #pragma unroll 5
        for (int k4 = 0; k4 < 15; ++k4) {
            float4 wv[2], hv[4];
            wv[0] = wL4[tj * 15 + k4];
            wv[1] = wL4[(tj + 32) * 15 + k4];
            #pragma unroll
            for (int bb = 0; bb < 4; ++bb) hv[bb] = hL4[(tb * 4 + bb) * 15 + k4];
            #pragma unroll
            for (int jj = 0; jj < 2; ++jj) {
                #pragma unroll
                for (int bb = 0; bb < 4; ++bb) {
                    acc[jj][bb] = fmaf(wv[jj].x, hv[bb].x, acc[jj][bb]);
                    acc[jj][bb] = fmaf(wv[jj].y, hv[bb].y, acc[jj][bb]);
                    acc[jj][bb] = fmaf(wv[jj].z, hv[bb].z, acc[jj][bb]);
                    acc[jj][bb] = fmaf(wv[jj].w, hv[bb].w, acc[jj][bb]);
                }
            }
        }
    }

    #pragma unroll
    for (int jj = 0; jj < 2; ++jj) {
        int j = j0 + tj + 32 * jj;
        if (j >= NROWS) continue;
        float bv = (j < NG) ? bg[j] : bsn[j - NG];
        #pragma unroll
        for (int bb = 0; bb < 4; ++bb) {
            int b = tb * 4 + bb;
            float v = acc[jj][bb] + bv;
            float* op = (j < NG) ? (out + (long)b * NG + j)
                                 : (out + (long)B * NG + (long)b * NS + (j - NG));
            *op = v;
        }
    }
}

__global__ __launch_bounds__(1024) void log_softmax_rows(float* __restrict__ out) {
    int row = blockIdx.x;  // 0..63
    int head = row >> 5, b = row & 31;
    float* p = out + (long)head * (B * NG) + (long)b * NG;
    float4* p4 = (float4*)p;  // 6250 float4 per row
    int tid = threadIdx.x;
    __shared__ float red[16];
    float m = -INFINITY;
    for (int i = tid; i < 6250; i += 1024) {
        float4 v = p4[i];
        m = fmaxf(fmaxf(fmaxf(m, v.x), v.y), fmaxf(v.z, v.w));
    }
    #pragma unroll
    for (int o = 32; o; o >>= 1) m = fmaxf(m, __shfl_xor(m, o));
    if ((tid & 63) == 0) red[tid >> 6] = m;
    __syncthreads();
    if (tid == 0) {
        float mm = red[0];
        for (int i = 1; i < 16; ++i) mm = fmaxf(mm, red[i]);
        red[0] = mm;
    }
    __syncthreads();
    m = red[0];
    __syncthreads();
    float s = 0.f;
    for (int i = tid; i < 6250; i += 1024) {
        float4 v = p4[i];
        s += __expf(v.x - m) + __expf(v.y - m) + __expf(v.z - m) + __expf(v.w - m);
    }
    #pragma unroll
    for (int o = 32; o; o >>= 1) s += __shfl_xor(s, o);
    if ((tid & 63) == 0) red[tid >> 6] = s;
    __syncthreads();
    if (tid == 0) {
        float ss = 0.f;
        for (int i = 0; i < 16; ++i) ss += red[i];
        red[0] = m + __logf(ss);
    }
    __syncthreads();
    float lse = red[0];
    for (int i = tid; i < 6250; i += 1024) {
        float4 v = p4[i];
        v.x -= lse; v.y -= lse; v.z -= lse; v.w -= lse;
        p4[i] = v;
    }
}

extern "C" void kernel_launch(void* const* d_in, const int* in_sizes, int n_in,
                              void* d_out, int out_size, void* d_ws, size_t ws_size,
                              hipStream_t stream) {
    const float* x     = (const float*)d_in[0];
    const int*   ei    = (const int*)d_in[1];
    const int*   et    = (const int*)d_in[2];
    const int*   cur   = (const int*)d_in[3];
    const float* basis = (const float*)d_in[4];
    const float* comp  = (const float*)d_in[5];
    const float* root  = (const float*)d_in[6];
    const float* bias  = (const float*)d_in[7];
    const float* wg    = (const float*)d_in[8];
    const float* bgl   = (const float*)d_in[9];
    const float* wsn   = (const float*)d_in[10];
    const float* bsn   = (const float*)d_in[11];
    float* out  = (float*)d_out;
    float* wsum = (float*)d_ws;                 // 48000
    float* wcnt = wsum + B * R * D;             // 160
    float* hcp  = wcnt + B * R;                 // 9600
    float* part = out;                          // 345600 floats (scratch, overwritten later)
    float* U    = out + 400000;                 // 57600 floats (scratch, overwritten later)

    hipMemsetAsync(d_ws, 0, (size_t)(B * R * D + B * R) * sizeof(float), stream);
    edge_scan<<<(NE + 255) / 256, 256, 0, stream>>>(ei, et, x, cur, wsum, wcnt);
    stage_u<<<B, 320, 0, stream>>>(x, cur, comp, wsum, wcnt, U);
    rgcn_part<<<NKC, 320, 0, stream>>>(root, basis, U, part);
    finish_hc<<<B, 320, 0, stream>>>(part, bias, hcp);
    head_gemm<<<(NROWS + TJ - 1) / TJ, 256, 0, stream>>>(hcp, wg, bgl, wsn, bsn, out);
    log_softmax_rows<<<64, 1024, 0, stream>>>(out);
}

// Round 3
// 93.164 us; speedup vs baseline: 2.0943x; 1.1435x over previous
//
#include <hip/hip_runtime.h>
#include <hip/hip_bf16.h>
#include <math.h>

#define NN 60000
#define D 300
#define R 5
#define NE 1000000
#define B 32
#define NG 25000
#define NS 25000
#define NROWS 50000
#define KCH 50         // d-rows per block in rgcn partial gemm
#define NKC 36         // 1800 / 50
#define HCP 304        // hc row padded to 304 (19 * 16)

typedef __bf16 bf16x8 __attribute__((ext_vector_type(8)));
typedef float f32x16 __attribute__((ext_vector_type(16)));

// ws layout (floats): wsum[48000], wcnt[160], then hcb (bf16, 32*304 = 9728 floats-worth)
// d_out tail scratch: part at out+0 (345600 floats), U at out+400000 (57600 floats);
// both consumed before head_gemm_mfma, which overwrites all of d_out.

__global__ void zero_ws(float4* __restrict__ p) {
    int i = blockIdx.x * 256 + threadIdx.x;
    if (i < 12040) p[i] = float4{0.f, 0.f, 0.f, 0.f};  // 48160 floats
}

__global__ void edge_scan(const int* __restrict__ ei, const int* __restrict__ et,
                          const float* __restrict__ x, const int* __restrict__ cur,
                          float* __restrict__ wsum, float* __restrict__ wcnt) {
    __shared__ unsigned int tbl[32];
    __shared__ int curl[B];
    int tid = threadIdx.x;
    if (tid < 32) tbl[tid] = 0u;
    __syncthreads();
    if (tid < B) {
        int c = cur[tid];
        curl[tid] = c;
        atomicOr(&tbl[(c >> 5) & 31], 1u << (c & 31));
    }
    __syncthreads();
    int e = blockIdx.x * blockDim.x + tid;
    if (e >= NE) return;
    int dst = ei[NE + e];
    if (!(tbl[(dst >> 5) & 31] & (1u << (dst & 31)))) return;  // bloom reject (~97%)
    int src = -1, r = 0;
    for (int b = 0; b < B; ++b) {
        if (dst == curl[b]) {
            if (src < 0) { src = ei[e]; r = et[e]; }
            atomicAdd(&wcnt[b * R + r], 1.0f);
            const float* xs = x + (long)src * D;
            float* sm = wsum + (b * R + r) * D;
            for (int d = 0; d < D; ++d) atomicAdd(&sm[d], xs[d]);
        }
    }
}

// Build U[b][1800] = concat(x[cur[b]], mc[0..4]) where mc[bb] = sum_r comp[r][bb]*mean[r]
__global__ void stage_u(const float* __restrict__ x, const int* __restrict__ cur,
                        const float* __restrict__ comp,
                        const float* __restrict__ wsum, const float* __restrict__ wcnt,
                        float* __restrict__ U) {
    int b = blockIdx.x, t = threadIdx.x;  // 320 threads
    __shared__ float cmp[R * R];
    __shared__ float inv[R];
    if (t < R * R) cmp[t] = comp[t];
    if (t < R) inv[t] = 1.0f / fmaxf(wcnt[b * R + t], 1.0f);
    __syncthreads();
    if (t >= D) return;
    int node = cur[b];
    U[(long)b * 1800 + t] = x[(long)node * D + t];
    float mean[R];
    #pragma unroll
    for (int r = 0; r < R; ++r) mean[r] = wsum[((long)b * R + r) * D + t] * inv[r];
    #pragma unroll
    for (int bb = 0; bb < R; ++bb) {
        float a = 0.f;
        #pragma unroll
        for (int r = 0; r < R; ++r) a = fmaf(cmp[r * R + bb], mean[r], a);
        U[(long)b * 1800 + 300 + bb * 300 + t] = a;
    }
}

// partial[kc][b][e] = sum_{d in chunk} U[b][d] * M[d][e],  M = [root; basis] stacked (1800 x 300)
__global__ __launch_bounds__(320) void rgcn_part(const float* __restrict__ root,
                                                 const float* __restrict__ basis,
                                                 const float* __restrict__ U,
                                                 float* __restrict__ part) {
    int kc = blockIdx.x, t = threadIdx.x;  // 320 threads, e = t
    __shared__ float uL[B * KCH];
    int d0 = kc * KCH;
    for (int i = t; i < B * KCH; i += 320) {
        int b = i / KCH, dd = i - b * KCH;
        uL[i] = U[(long)b * 1800 + d0 + dd];
    }
    __syncthreads();
    if (t >= D) return;
    const float* Mbase = (d0 < 300) ? (root + (long)d0 * D) : (basis + (long)(d0 - 300) * D);
    float acc[B] = {};
    #pragma unroll 5
    for (int i = 0; i < KCH; ++i) {
        float m = Mbase[(long)i * D + t];
        #pragma unroll
        for (int b = 0; b < B; ++b) acc[b] = fmaf(uL[b * KCH + i], m, acc[b]);
    }
    for (int b = 0; b < B; ++b) part[((long)kc * B + b) * D + t] = acc[b];
}

// hcb[b][t] (bf16, padded to 304) = relu(bias + sum_kc part)
__global__ void finish_hc(const float* __restrict__ part, const float* __restrict__ bias,
                          __bf16* __restrict__ hcb) {
    int b = blockIdx.x, t = threadIdx.x;  // 320 threads
    if (t >= HCP) return;
    float a = 0.f;
    if (t < D) {
        a = bias[t];
        for (int kc = 0; kc < NKC; ++kc) a += part[((long)kc * B + b) * D + t];
        a = fmaxf(a, 0.f);
    }
    hcb[b * HCP + t] = (__bf16)a;
}

// MFMA head GEMM: one wave = 32j x 32b output tile, K=300 (19 steps of 16).
// A = W rows (bf16-converted in-reg), B = hcb (preloaded into 19 frags).
__global__ __launch_bounds__(64) void head_gemm_mfma(
    const __bf16* __restrict__ hcb, const float* __restrict__ wg, const float* __restrict__ bg,
    const float* __restrict__ wsn, const float* __restrict__ bsn, float* __restrict__ out) {
    int l = threadIdx.x;
    int j0 = blockIdx.x * 32;
    int lm = l & 31, lh = l >> 5;

    // preload B frags: lane l holds hcb[b=lm][k = lh*8 + t + 16*s]
    bf16x8 bfrag[19];
    const __bf16* hrow = hcb + lm * HCP + lh * 8;
    #pragma unroll
    for (int s = 0; s < 19; ++s) bfrag[s] = *(const bf16x8*)(hrow + 16 * s);

    // A row pointer: lane l covers W row (j0+lm), k-offset lh*8
    int row = j0 + lm; if (row >= NROWS) row = NROWS - 1;
    const float* wrow = ((row < NG) ? (wg + (long)row * D) : (wsn + (long)(row - NG) * D)) + lh * 8;

    f32x16 acc = {};
    #pragma unroll
    for (int s = 0; s < 18; ++s) {
        float4 w0 = *(const float4*)(wrow + 16 * s);
        float4 w1 = *(const float4*)(wrow + 16 * s + 4);
        bf16x8 a;
        a[0] = (__bf16)w0.x; a[1] = (__bf16)w0.y; a[2] = (__bf16)w0.z; a[3] = (__bf16)w0.w;
        a[4] = (__bf16)w1.x; a[5] = (__bf16)w1.y; a[6] = (__bf16)w1.z; a[7] = (__bf16)w1.w;
        acc = __builtin_amdgcn_mfma_f32_32x32x16_bf16(a, bfrag[s], acc, 0, 0, 0);
    }
    // last step: k = 288..299 valid (12 of 16). lo half: 288..295 full; hi half: 296..299 + zeros.
    {
        float4 w0, w1;
        if (lh == 0) {
            w0 = *(const float4*)(wrow + 288);
            w1 = *(const float4*)(wrow + 292);
        } else {
            w0 = *(const float4*)(wrow + 288);  // = row base + 296
            w1 = float4{0.f, 0.f, 0.f, 0.f};
        }
        bf16x8 a;
        a[0] = (__bf16)w0.x; a[1] = (__bf16)w0.y; a[2] = (__bf16)w0.z; a[3] = (__bf16)w0.w;
        a[4] = (__bf16)w1.x; a[5] = (__bf16)w1.y; a[6] = (__bf16)w1.z; a[7] = (__bf16)w1.w;
        acc = __builtin_amdgcn_mfma_f32_32x32x16_bf16(a, bfrag[18], acc, 0, 0, 0);
    }

    // C layout: col(b) = lm, row(j within tile) = (r&3) + 8*(r>>2) + 4*lh
    int b = lm;
    #pragma unroll
    for (int r = 0; r < 16; ++r) {
        int j = j0 + (r & 3) + 8 * (r >> 2) + 4 * lh;
        if (j >= NROWS) continue;
        float bv = (j < NG) ? bg[j] : bsn[j - NG];
        float* op = (j < NG) ? (out + (long)b * NG + j)
                             : (out + (long)B * NG + (long)b * NS + (j - NG));
        *op = acc[r] + bv;
    }
}

__global__ __launch_bounds__(1024) void log_softmax_rows(float* __restrict__ out) {
    int row = blockIdx.x;  // 0..63
    int head = row >> 5, b = row & 31;
    float* p = out + (long)head * (B * NG) + (long)b * NG;
    float4* p4 = (float4*)p;  // 6250 float4 per row
    int tid = threadIdx.x;
    __shared__ float red[16];
    float m = -INFINITY;
    for (int i = tid; i < 6250; i += 1024) {
        float4 v = p4[i];
        m = fmaxf(fmaxf(fmaxf(m, v.x), v.y), fmaxf(v.z, v.w));
    }
    #pragma unroll
    for (int o = 32; o; o >>= 1) m = fmaxf(m, __shfl_xor(m, o));
    if ((tid & 63) == 0) red[tid >> 6] = m;
    __syncthreads();
    if (tid == 0) {
        float mm = red[0];
        for (int i = 1; i < 16; ++i) mm = fmaxf(mm, red[i]);
        red[0] = mm;
    }
    __syncthreads();
    m = red[0];
    __syncthreads();
    float s = 0.f;
    for (int i = tid; i < 6250; i += 1024) {
        float4 v = p4[i];
        s += __expf(v.x - m) + __expf(v.y - m) + __expf(v.z - m) + __expf(v.w - m);
    }
    #pragma unroll
    for (int o = 32; o; o >>= 1) s += __shfl_xor(s, o);
    if ((tid & 63) == 0) red[tid >> 6] = s;
    __syncthreads();
    if (tid == 0) {
        float ss = 0.f;
        for (int i = 0; i < 16; ++i) ss += red[i];
        red[0] = m + __logf(ss);
    }
    __syncthreads();
    float lse = red[0];
    for (int i = tid; i < 6250; i += 1024) {
        float4 v = p4[i];
        v.x -= lse; v.y -= lse; v.z -= lse; v.w -= lse;
        p4[i] = v;
    }
}

extern "C" void kernel_launch(void* const* d_in, const int* in_sizes, int n_in,
                              void* d_out, int out_size, void* d_ws, size_t ws_size,
                              hipStream_t stream) {
    const float* x     = (const float*)d_in[0];
    const int*   ei    = (const int*)d_in[1];
    const int*   et    = (const int*)d_in[2];
    const int*   cur   = (const int*)d_in[3];
    const float* basis = (const float*)d_in[4];
    const float* comp  = (const float*)d_in[5];
    const float* root  = (const float*)d_in[6];
    const float* bias  = (const float*)d_in[7];
    const float* wg    = (const float*)d_in[8];
    const float* bgl   = (const float*)d_in[9];
    const float* wsn   = (const float*)d_in[10];
    const float* bsn   = (const float*)d_in[11];
    float* out  = (float*)d_out;
    float* wsum = (float*)d_ws;                 // 48000 floats
    float* wcnt = wsum + B * R * D;             // 160 floats
    __bf16* hcb = (__bf16*)(wcnt + B * R);      // 32*304 bf16 (19456 B), 16B-aligned
    float* part = out;                          // 345600 floats (scratch, overwritten later)
    float* U    = out + 400000;                 // 57600 floats (scratch, overwritten later)

    zero_ws<<<48, 256, 0, stream>>>((float4*)d_ws);
    edge_scan<<<(NE + 255) / 256, 256, 0, stream>>>(ei, et, x, cur, wsum, wcnt);
    stage_u<<<B, 320, 0, stream>>>(x, cur, comp, wsum, wcnt, U);
    rgcn_part<<<NKC, 320, 0, stream>>>(root, basis, U, part);
    finish_hc<<<B, 320, 0, stream>>>(part, bias, hcb);
    head_gemm_mfma<<<(NROWS + 31) / 32, 64, 0, stream>>>(hcb, wg, bgl, wsn, bsn, out);
    log_softmax_rows<<<64, 1024, 0, stream>>>(out);
}

// Round 4
// 75.971 us; speedup vs baseline: 2.5682x; 1.2263x over previous
//
#include <hip/hip_runtime.h>
#include <hip/hip_bf16.h>
#include <math.h>

#define NN 60000
#define D 300
#define R 5
#define NE 1000000
#define B 32
#define NG 25000
#define NS 25000
#define NROWS 50000
#define KCH 50         // d-rows per block in rgcn partial gemm
#define NKC 36         // 1800 / 50
#define HCP 304        // hc row padded to 304 (19 * 16)
#define MCAP 1000000   // matched-edge list capacity

typedef __bf16 bf16x8 __attribute__((ext_vector_type(8)));
typedef float f32x16 __attribute__((ext_vector_type(16)));

// ws layout (floats):
//   wsum  [0, 48000)
//   wcnt  [48000, 48160)
//   hcb   bf16 at float-offset 48160 (32*304 bf16 = 4864 floats) -> [48160, 53024)
//   mcnt  int at 53024
//   mlist int2 at 53028 (8B-aligned: 53028*4 = 212112), MCAP entries = 8 MB
// d_out tail scratch: part at out+0 (345600 floats), U at out+400000 (57600 floats);
// both consumed before head_gemm_mfma, which overwrites all of d_out.

__global__ void zero_ws(float4* __restrict__ p) {
    int i = blockIdx.x * 256 + threadIdx.x;
    if (i < 12040) p[i] = float4{0.f, 0.f, 0.f, 0.f};  // [0, 48160) floats
    if (i == 0) ((int*)p)[53024] = 0;                   // mcnt
}

// Pass 1: scan dst, compact matching edges into mlist as (src, b*R+r).
__global__ __launch_bounds__(256) void edge_scan2(
        const int* __restrict__ ei, const int* __restrict__ et,
        const int* __restrict__ cur,
        float* __restrict__ wcnt, int2* __restrict__ mlist, int* __restrict__ mcnt) {
    __shared__ unsigned int tbl[32];
    __shared__ int curl[B];
    int tid = threadIdx.x;
    if (tid < 32) tbl[tid] = 0u;
    __syncthreads();
    if (tid < B) {
        int c = cur[tid];
        curl[tid] = c;
        atomicOr(&tbl[(c >> 5) & 31], 1u << (c & 31));
    }
    __syncthreads();
    long base = ((long)blockIdx.x * 256 + tid) * 4;
    if (base >= NE) return;
    int ds[4];
    if (base + 4 <= NE) {
        int4 d4 = *(const int4*)(ei + NE + base);
        ds[0] = d4.x; ds[1] = d4.y; ds[2] = d4.z; ds[3] = d4.w;
    } else {
        for (int k = 0; k < 4; ++k) ds[k] = (base + k < NE) ? ei[NE + base + k] : -1;
    }
    #pragma unroll
    for (int k = 0; k < 4; ++k) {
        int dst = ds[k];
        if (dst < 0) continue;
        if (!(tbl[(dst >> 5) & 31] & (1u << (dst & 31)))) continue;  // bloom reject
        int e = (int)base + k;
        int r = -1, s = 0;
        for (int b = 0; b < B; ++b) {
            if (dst == curl[b]) {
                if (r < 0) { r = et[e]; s = ei[e]; }
                int slot = b * R + r;
                atomicAdd(&wcnt[slot], 1.0f);
                int pos = atomicAdd(mcnt, 1);
                if (pos < MCAP) mlist[pos] = int2{s, slot};
            }
        }
    }
}

// Pass 2: one block per matched edge (block-stride): coalesced 300-float row add.
__global__ __launch_bounds__(256) void edge_accum(
        const int2* __restrict__ mlist, const int* __restrict__ mcnt,
        const float* __restrict__ x, float* __restrict__ wsum) {
    int n = *mcnt; if (n > MCAP) n = MCAP;
    for (int m = blockIdx.x; m < n; m += gridDim.x) {
        int2 p = mlist[m];
        const float* xs = x + (long)p.x * D;
        float* sm = wsum + (long)p.y * D;
        for (int t = threadIdx.x; t < D; t += 256) atomicAdd(&sm[t], xs[t]);
    }
}

// Build U[b][1800] = concat(x[cur[b]], mc[0..4]) where mc[bb] = sum_r comp[r][bb]*mean[r]
__global__ void stage_u(const float* __restrict__ x, const int* __restrict__ cur,
                        const float* __restrict__ comp,
                        const float* __restrict__ wsum, const float* __restrict__ wcnt,
                        float* __restrict__ U) {
    int b = blockIdx.x, t = threadIdx.x;  // 320 threads
    __shared__ float cmp[R * R];
    __shared__ float inv[R];
    if (t < R * R) cmp[t] = comp[t];
    if (t < R) inv[t] = 1.0f / fmaxf(wcnt[b * R + t], 1.0f);
    __syncthreads();
    if (t >= D) return;
    int node = cur[b];
    U[(long)b * 1800 + t] = x[(long)node * D + t];
    float mean[R];
    #pragma unroll
    for (int r = 0; r < R; ++r) mean[r] = wsum[((long)b * R + r) * D + t] * inv[r];
    #pragma unroll
    for (int bb = 0; bb < R; ++bb) {
        float a = 0.f;
        #pragma unroll
        for (int r = 0; r < R; ++r) a = fmaf(cmp[r * R + bb], mean[r], a);
        U[(long)b * 1800 + 300 + bb * 300 + t] = a;
    }
}

// partial[kc][b][e] = sum_{d in chunk} U[b][d] * M[d][e],  M = [root; basis] stacked (1800 x 300)
__global__ __launch_bounds__(320) void rgcn_part(const float* __restrict__ root,
                                                 const float* __restrict__ basis,
                                                 const float* __restrict__ U,
                                                 float* __restrict__ part) {
    int kc = blockIdx.x, t = threadIdx.x;  // 320 threads, e = t
    __shared__ float uL[B * KCH];
    int d0 = kc * KCH;
    for (int i = t; i < B * KCH; i += 320) {
        int b = i / KCH, dd = i - b * KCH;
        uL[i] = U[(long)b * 1800 + d0 + dd];
    }
    __syncthreads();
    if (t >= D) return;
    const float* Mbase = (d0 < 300) ? (root + (long)d0 * D) : (basis + (long)(d0 - 300) * D);
    float acc[B] = {};
    #pragma unroll 5
    for (int i = 0; i < KCH; ++i) {
        float m = Mbase[(long)i * D + t];
        #pragma unroll
        for (int b = 0; b < B; ++b) acc[b] = fmaf(uL[b * KCH + i], m, acc[b]);
    }
    for (int b = 0; b < B; ++b) part[((long)kc * B + b) * D + t] = acc[b];
}

// hcb[b][t] (bf16, padded to 304) = relu(bias + sum_kc part)
__global__ void finish_hc(const float* __restrict__ part, const float* __restrict__ bias,
                          __bf16* __restrict__ hcb) {
    int b = blockIdx.x, t = threadIdx.x;  // 320 threads
    if (t >= HCP) return;
    float a = 0.f;
    if (t < D) {
        a = bias[t];
        for (int kc = 0; kc < NKC; ++kc) a += part[((long)kc * B + b) * D + t];
        a = fmaxf(a, 0.f);
    }
    hcb[b * HCP + t] = (__bf16)a;
}

// MFMA head GEMM: one wave = 32j x 32b output tile, K=300 (19 steps of 16).
__global__ __launch_bounds__(64) void head_gemm_mfma(
    const __bf16* __restrict__ hcb, const float* __restrict__ wg, const float* __restrict__ bg,
    const float* __restrict__ wsn, const float* __restrict__ bsn, float* __restrict__ out) {
    int l = threadIdx.x;
    int j0 = blockIdx.x * 32;
    int lm = l & 31, lh = l >> 5;

    bf16x8 bfrag[19];
    const __bf16* hrow = hcb + lm * HCP + lh * 8;
    #pragma unroll
    for (int s = 0; s < 19; ++s) bfrag[s] = *(const bf16x8*)(hrow + 16 * s);

    int row = j0 + lm; if (row >= NROWS) row = NROWS - 1;
    const float* wrow = ((row < NG) ? (wg + (long)row * D) : (wsn + (long)(row - NG) * D)) + lh * 8;

    f32x16 acc = {};
    #pragma unroll
    for (int s = 0; s < 18; ++s) {
        float4 w0 = *(const float4*)(wrow + 16 * s);
        float4 w1 = *(const float4*)(wrow + 16 * s + 4);
        bf16x8 a;
        a[0] = (__bf16)w0.x; a[1] = (__bf16)w0.y; a[2] = (__bf16)w0.z; a[3] = (__bf16)w0.w;
        a[4] = (__bf16)w1.x; a[5] = (__bf16)w1.y; a[6] = (__bf16)w1.z; a[7] = (__bf16)w1.w;
        acc = __builtin_amdgcn_mfma_f32_32x32x16_bf16(a, bfrag[s], acc, 0, 0, 0);
    }
    {
        float4 w0, w1;
        if (lh == 0) {
            w0 = *(const float4*)(wrow + 288);
            w1 = *(const float4*)(wrow + 292);
        } else {
            w0 = *(const float4*)(wrow + 288);  // = row base + 296
            w1 = float4{0.f, 0.f, 0.f, 0.f};
        }
        bf16x8 a;
        a[0] = (__bf16)w0.x; a[1] = (__bf16)w0.y; a[2] = (__bf16)w0.z; a[3] = (__bf16)w0.w;
        a[4] = (__bf16)w1.x; a[5] = (__bf16)w1.y; a[6] = (__bf16)w1.z; a[7] = (__bf16)w1.w;
        acc = __builtin_amdgcn_mfma_f32_32x32x16_bf16(a, bfrag[18], acc, 0, 0, 0);
    }

    int b = lm;
    #pragma unroll
    for (int r = 0; r < 16; ++r) {
        int j = j0 + (r & 3) + 8 * (r >> 2) + 4 * lh;
        if (j >= NROWS) continue;
        float bv = (j < NG) ? bg[j] : bsn[j - NG];
        float* op = (j < NG) ? (out + (long)b * NG + j)
                             : (out + (long)B * NG + (long)b * NS + (j - NG));
        *op = acc[r] + bv;
    }
}

__global__ __launch_bounds__(1024) void log_softmax_rows(float* __restrict__ out) {
    int row = blockIdx.x;  // 0..63
    int head = row >> 5, b = row & 31;
    float* p = out + (long)head * (B * NG) + (long)b * NG;
    float4* p4 = (float4*)p;  // 6250 float4 per row
    int tid = threadIdx.x;
    __shared__ float red[16];
    float m = -INFINITY;
    for (int i = tid; i < 6250; i += 1024) {
        float4 v = p4[i];
        m = fmaxf(fmaxf(fmaxf(m, v.x), v.y), fmaxf(v.z, v.w));
    }
    #pragma unroll
    for (int o = 32; o; o >>= 1) m = fmaxf(m, __shfl_xor(m, o));
    if ((tid & 63) == 0) red[tid >> 6] = m;
    __syncthreads();
    if (tid == 0) {
        float mm = red[0];
        for (int i = 1; i < 16; ++i) mm = fmaxf(mm, red[i]);
        red[0] = mm;
    }
    __syncthreads();
    m = red[0];
    __syncthreads();
    float s = 0.f;
    for (int i = tid; i < 6250; i += 1024) {
        float4 v = p4[i];
        s += __expf(v.x - m) + __expf(v.y - m) + __expf(v.z - m) + __expf(v.w - m);
    }
    #pragma unroll
    for (int o = 32; o; o >>= 1) s += __shfl_xor(s, o);
    if ((tid & 63) == 0) red[tid >> 6] = s;
    __syncthreads();
    if (tid == 0) {
        float ss = 0.f;
        for (int i = 0; i < 16; ++i) ss += red[i];
        red[0] = m + __logf(ss);
    }
    __syncthreads();
    float lse = red[0];
    for (int i = tid; i < 6250; i += 1024) {
        float4 v = p4[i];
        v.x -= lse; v.y -= lse; v.z -= lse; v.w -= lse;
        p4[i] = v;
    }
}

extern "C" void kernel_launch(void* const* d_in, const int* in_sizes, int n_in,
                              void* d_out, int out_size, void* d_ws, size_t ws_size,
                              hipStream_t stream) {
    const float* x     = (const float*)d_in[0];
    const int*   ei    = (const int*)d_in[1];
    const int*   et    = (const int*)d_in[2];
    const int*   cur   = (const int*)d_in[3];
    const float* basis = (const float*)d_in[4];
    const float* comp  = (const float*)d_in[5];
    const float* root  = (const float*)d_in[6];
    const float* bias  = (const float*)d_in[7];
    const float* wg    = (const float*)d_in[8];
    const float* bgl   = (const float*)d_in[9];
    const float* wsn   = (const float*)d_in[10];
    const float* bsn   = (const float*)d_in[11];
    float* out  = (float*)d_out;
    float* wsf  = (float*)d_ws;
    float* wsum = wsf;                           // [0, 48000)
    float* wcnt = wsf + 48000;                   // [48000, 48160)
    __bf16* hcb = (__bf16*)(wsf + 48160);        // 32*304 bf16
    int*   mcnt = (int*)(wsf + 53024);           // 1 int
    int2*  mlist = (int2*)(wsf + 53028);         // MCAP int2 (8 MB)
    float* part = out;                           // scratch, overwritten later
    float* U    = out + 400000;                  // scratch, overwritten later

    zero_ws<<<48, 256, 0, stream>>>((float4*)d_ws);
    edge_scan2<<<977, 256, 0, stream>>>(ei, et, cur, wcnt, mlist, mcnt);
    edge_accum<<<512, 256, 0, stream>>>(mlist, mcnt, x, wsum);
    stage_u<<<B, 320, 0, stream>>>(x, cur, comp, wsum, wcnt, U);
    rgcn_part<<<NKC, 320, 0, stream>>>(root, basis, U, part);
    finish_hc<<<B, 320, 0, stream>>>(part, bias, hcb);
    head_gemm_mfma<<<(NROWS + 31) / 32, 64, 0, stream>>>(hcb, wg, bgl, wsn, bsn, out);
    log_softmax_rows<<<64, 1024, 0, stream>>>(out);
}